// Round 12
// baseline (534.230 us; speedup 1.0000x reference)
//
#include <hip/hip_runtime.h>
#include <math.h>

#define T_ 64
#define N_ 40
#define D_ 4
#define H_ 256
#define R_ 64
#define E_ 1560
#define TE_ (T_*E_)
#define TN_ (T_*N_)

typedef unsigned short us;
typedef short short8 __attribute__((ext_vector_type(8)));
typedef float f32x4 __attribute__((ext_vector_type(4)));

__device__ __forceinline__ float elu_f(float x){ return x > 0.f ? x : (__expf(x) - 1.f); }
__device__ __forceinline__ float sig_f(float x){ return 1.f/(1.f+__expf(-x)); }
__device__ __forceinline__ float tanh_f(float x){ return 2.f/(1.f+__expf(-2.f*x)) - 1.f; }
__device__ __forceinline__ float dot4(float4 a, float4 b){ return a.x*b.x + a.y*b.y + a.z*b.z + a.w*b.w; }

__device__ __forceinline__ float bf2f(us u){ return __uint_as_float(((unsigned int)u) << 16); }
__device__ __forceinline__ us f2bf(float f){
    unsigned int u = __float_as_uint(f);
    u += 0x7FFFu + ((u >> 16) & 1u);
    return (us)(u >> 16);
}
__device__ __forceinline__ float4 ld4f(const float* p){ return *(const float4*)p; }
__device__ __forceinline__ float4 ld4f(const us* p){
    ushort4 v = *(const ushort4*)p;
    return make_float4(bf2f(v.x), bf2f(v.y), bf2f(v.z), bf2f(v.w));
}
__device__ __forceinline__ void st4f(float* p, float4 v){ *(float4*)p = v; }
__device__ __forceinline__ void st4f(us* p, float4 v){
    ushort4 o; o.x = f2bf(v.x); o.y = f2bf(v.y); o.z = f2bf(v.z); o.w = f2bf(v.w);
    *(ushort4*)p = o;
}

__device__ __forceinline__ void gld16(void* lds, const void* g){
    __builtin_amdgcn_global_load_lds((const __attribute__((address_space(1))) unsigned int*)g,
                                     (__attribute__((address_space(3))) unsigned int*)lds,
                                     16, 0, 0);
}

__device__ __forceinline__ void wsplit1(const float* W, us* hi, us* lo, int i){
    const float w = W[i];
    const us h = f2bf(w);
    hi[i] = h;
    lo[i] = f2bf(w - bf2f(h));
}

// Fragment-contiguous W' packing for the reg-W GEMM core.
// Dest index i = fh*8192 + k*1024 + mt*512 + lane*8 + jj holds
// W[R*stride + colOff + K], R = fh*32 + mt*16 + (lane&15),
// K = k*32 + (lane>>4)*8 + jj -> per-(k,mt) fragment load is coalesced.
__device__ __forceinline__ void wsplitF(const float* __restrict__ W, int stride, int colOff,
                                        us* hi, us* lo, int i){
    const int jj   = i & 7;
    const int lane = (i >> 3) & 63;
    const int mt   = (i >> 9) & 1;
    const int k    = (i >> 10) & 7;
    const int fh   = i >> 13;
    const int R = fh * 32 + mt * 16 + (lane & 15);
    const int K = k * 32 + (lane >> 4) * 8 + jj;
    const float w = W[(size_t)R * stride + colOff + K];
    const us h = f2bf(w);
    hi[i] = h;
    lo[i] = f2bf(w - bf2f(h));
}

// 5 packed GEMM weights + 2 linear LSTM Whh splits.
__global__ __launch_bounds__(256)
void wsplit_all(const float* __restrict__ s0, us* h0, us* l0,
                const float* __restrict__ s1, us* h1, us* l1,
                const float* __restrict__ s2, us* h2, us* l2,
                const float* __restrict__ s3, us* h3, us* l3,
                const float* __restrict__ s4, us* h4, us* l4,
                const float* __restrict__ s5, us* h5, us* l5,
                const float* __restrict__ s6, us* h6, us* l6)
{
    int i = blockIdx.x * 256 + threadIdx.x;
    if (i < 65536) { wsplitF(s0, 256,   0, h0, l0, i); return; } i -= 65536;
    if (i < 65536) { wsplitF(s1, 768, 512, h1, l1, i); return; } i -= 65536;
    if (i < 65536) { wsplitF(s2, 256,   0, h2, l2, i); return; } i -= 65536;
    if (i < 65536) { wsplitF(s3, 256,   0, h3, l3, i); return; } i -= 65536;
    if (i < 65536) { wsplitF(s4, 256,   0, h4, l4, i); return; } i -= 65536;
    if (i < 16384) { wsplit1(s5, h5, l5, i); return; } i -= 16384;
    wsplit1(s6, h6, l6, i);
}

__global__ __launch_bounds__(256)
void mlp1_kernel(const float* __restrict__ x,
                 const float* __restrict__ W1, const float* __restrict__ b1,
                 const float* __restrict__ W2, const float* __restrict__ b2,
                 us* __restrict__ hout)
{
    __shared__ float xs[8][4];
    __shared__ float h1[8][256];
    const int tid = threadIdx.x;
    const int r0  = blockIdx.x * 8;

    if (tid < 32) xs[tid >> 2][tid & 3] = x[r0 * 4 + tid];
    __syncthreads();

    const float4 w1 = *(const float4*)&W1[tid * 4];
    const float bb1 = b1[tid];
    #pragma unroll
    for (int row = 0; row < 8; ++row) {
        float v = bb1 + xs[row][0]*w1.x + xs[row][1]*w1.y + xs[row][2]*w1.z + xs[row][3]*w1.w;
        h1[row][tid] = elu_f(v);
    }
    __syncthreads();

    float acc[8];
    const float bb2 = b2[tid];
    #pragma unroll
    for (int row = 0; row < 8; ++row) acc[row] = bb2;
    const float* w2row = W2 + (size_t)tid * 256;
    for (int k4 = 0; k4 < 64; ++k4) {
        const float4 w = *(const float4*)&w2row[k4 * 4];
        #pragma unroll
        for (int row = 0; row < 8; ++row) {
            const float4 hh = *(const float4*)&h1[row][k4 * 4];
            acc[row] += dot4(hh, w);
        }
    }
    #pragma unroll
    for (int row = 0; row < 8; ++row)
        hout[(size_t)(r0 + row) * 256 + tid] = f2bf(elu_f(acc[row]));
}

// ---------------------------------------------------------------------------
// Node-level projection: P[n, part*256 + j] = sum_k A[n,k] * W[j, part*256+k]
// ---------------------------------------------------------------------------
__global__ __launch_bounds__(256)
void node_proj(const us* __restrict__ A, const float* __restrict__ W,
               int wstride, float* __restrict__ P)
{
    __shared__ float As[16][64];
    __shared__ float Ws[16][64];

    const int tid  = threadIdx.x;
    const int am   = tid >> 2;
    const int gm   = blockIdx.x * 64 + am;
    const int part = blockIdx.y >> 2;
    const int wq   = blockIdx.y & 3;

    const us* aptr = A + (size_t)gm * 256;
    const float* wptr = W + (size_t)(wq * 64 + am) * wstride + part * 256;

    const int tx = tid & 15, ty = tid >> 4;
    float acc[4][4] = {};

    for (int k0 = 0; k0 < 256; k0 += 16) {
        const float4 a4 = ld4f(aptr + k0 + (tid & 3) * 4);
        const float4 w4 = *(const float4*)(wptr + k0 + (tid & 3) * 4);

        __syncthreads();
        const int ak = (tid & 3) * 4;
        As[ak+0][am] = a4.x; As[ak+1][am] = a4.y; As[ak+2][am] = a4.z; As[ak+3][am] = a4.w;
        Ws[ak+0][am] = w4.x; Ws[ak+1][am] = w4.y; Ws[ak+2][am] = w4.z; Ws[ak+3][am] = w4.w;
        __syncthreads();

        #pragma unroll
        for (int kq = 0; kq < 16; ++kq) {
            const float4 av = *(const float4*)&As[kq][ty * 4];
            const float4 wv = *(const float4*)&Ws[kq][tx * 4];
            const float a_[4] = {av.x, av.y, av.z, av.w};
            const float w_[4] = {wv.x, wv.y, wv.z, wv.w};
            #pragma unroll
            for (int i = 0; i < 4; ++i)
                #pragma unroll
                for (int j = 0; j < 4; ++j)
                    acc[i][j] += a_[i] * w_[j];
        }
    }

    const int gn = part * 256 + wq * 64 + tx * 4;
    #pragma unroll
    for (int i = 0; i < 4; ++i) {
        const int row = blockIdx.x * 64 + ty * 4 + i;
        float4 o;
        o.x = acc[i][0]; o.y = acc[i][1]; o.z = acc[i][2]; o.w = acc[i][3];
        *(float4*)(P + (size_t)row * 512 + gn) = o;
    }
}

// ---------------------------------------------------------------------------
// Round-20 GEMM core (round-8 verified). Round-24 addition: CORE_DUAL runs
// the two INDEPENDENT units (fwd/rev Wih, both reading the same G2 panel)
// in one merged k-loop: 8 W-loads in flight + 32 MFMA per step -> 2x the
// memory-level parallelism per latency window, no extra LDS, same TLP.
// Per-output accumulation order unchanged (k asc, hi then lo each stream).
// ---------------------------------------------------------------------------
#define VM0   0x3F70   // s_waitcnt vmcnt(0)

#define GEMM_CORE64(WHp, WLp)                                                            \
    {                                                                                    \
        const us* wbh = (WHp) + w * 8192 + lane * 8;                                     \
        const us* wbl = (WLp) + w * 8192 + lane * 8;                                     \
        _Pragma("unroll")                                                                \
        for (int k = 0; k < 8; ++k) {                                                    \
            short8 wh[2], wl[2], ef[4];                                                  \
            _Pragma("unroll")                                                            \
            for (int mt = 0; mt < 2; ++mt) {                                             \
                wh[mt] = *(const short8*)(wbh + (k * 2 + mt) * 512);                     \
                wl[mt] = *(const short8*)(wbl + (k * 2 + mt) * 512);                     \
            }                                                                            \
            _Pragma("unroll")                                                            \
            for (int nt = 0; nt < 4; ++nt)                                               \
                ef[nt] = *(const short8*)(AG + k * 4096 + nt * 1024 + ml * 64 + qs16);   \
            __builtin_amdgcn_s_setprio(1);                                               \
            _Pragma("unroll")                                                            \
            for (int nt = 0; nt < 4; ++nt)                                               \
                _Pragma("unroll")                                                        \
                for (int mt = 0; mt < 2; ++mt) {                                         \
                    acc[mt][nt] = __builtin_amdgcn_mfma_f32_16x16x32_bf16(               \
                        wh[mt], ef[nt], acc[mt][nt], 0, 0, 0);                           \
                    acc[mt][nt] = __builtin_amdgcn_mfma_f32_16x16x32_bf16(               \
                        wl[mt], ef[nt], acc[mt][nt], 0, 0, 0);                           \
                }                                                                        \
            __builtin_amdgcn_s_setprio(0);                                               \
        }                                                                                \
    }

#define CORE_DUAL(WHf, WLf, WHr, WLr)                                                    \
    {                                                                                    \
        const us* wbhf = (WHf) + w * 8192 + lane * 8;                                    \
        const us* wblf = (WLf) + w * 8192 + lane * 8;                                    \
        const us* wbhr = (WHr) + w * 8192 + lane * 8;                                    \
        const us* wblr = (WLr) + w * 8192 + lane * 8;                                    \
        _Pragma("unroll")                                                                \
        for (int k = 0; k < 8; ++k) {                                                    \
            short8 whf[2], wlf[2], whr[2], wlr[2], ef[4];                                \
            _Pragma("unroll")                                                            \
            for (int mt = 0; mt < 2; ++mt) {                                             \
                whf[mt] = *(const short8*)(wbhf + (k * 2 + mt) * 512);                   \
                wlf[mt] = *(const short8*)(wblf + (k * 2 + mt) * 512);                   \
                whr[mt] = *(const short8*)(wbhr + (k * 2 + mt) * 512);                   \
                wlr[mt] = *(const short8*)(wblr + (k * 2 + mt) * 512);                   \
            }                                                                            \
            _Pragma("unroll")                                                            \
            for (int nt = 0; nt < 4; ++nt)                                               \
                ef[nt] = *(const short8*)(AG + k * 4096 + nt * 1024 + ml * 64 + qs16);   \
            __builtin_amdgcn_s_setprio(1);                                               \
            _Pragma("unroll")                                                            \
            for (int nt = 0; nt < 4; ++nt)                                               \
                _Pragma("unroll")                                                        \
                for (int mt = 0; mt < 2; ++mt) {                                         \
                    acc[mt][nt] = __builtin_amdgcn_mfma_f32_16x16x32_bf16(               \
                        whf[mt], ef[nt], acc[mt][nt], 0, 0, 0);                          \
                    acc[mt][nt] = __builtin_amdgcn_mfma_f32_16x16x32_bf16(               \
                        wlf[mt], ef[nt], acc[mt][nt], 0, 0, 0);                          \
                    accR[mt][nt] = __builtin_amdgcn_mfma_f32_16x16x32_bf16(              \
                        whr[mt], ef[nt], accR[mt][nt], 0, 0, 0);                         \
                    accR[mt][nt] = __builtin_amdgcn_mfma_f32_16x16x32_bf16(              \
                        wlr[mt], ef[nt], accR[mt][nt], 0, 0, 0);                         \
                }                                                                        \
            __builtin_amdgcn_s_setprio(0);                                               \
        }                                                                                \
    }

// mlp2 layer 2 with the edge gather+elu FUSED into the A-panel prologue
// (round-8 verified, unchanged).
__global__ __launch_bounds__(512, 4)
void gemm_bf(const float* __restrict__ Ptab, const float* __restrict__ b1,
             const int* __restrict__ send, const int* __restrict__ recv,
             const us* __restrict__ WH, const us* __restrict__ WL,
             const float* __restrict__ bias2, us* __restrict__ C)
{
    __shared__ char AG[32768];

    const int tid = threadIdx.x, lane = tid & 63, w = tid >> 6;  // w 0..7
    const int ml = lane & 15, q = lane >> 4;
    const int qs16 = (q ^ ((ml >> 1) & 3)) * 16;
    const int bx = blockIdx.x;

    // prologue: gather + elu + pack into swizzled A panel
    {
        int srw[4], rrw[4];
        #pragma unroll
        for (int nt = 0; nt < 4; ++nt) {
            const int row = bx * 64 + nt * 16 + ml;
            const int t = row / E_;
            const int e = row - t * E_;
            srw[nt] = t * N_ + send[e];
            rrw[nt] = t * N_ + recv[e];
        }
        #pragma unroll
        for (int mt = 0; mt < 2; ++mt) {
            const int col = w * 32 + mt * 16 + q * 4;
            const float4 bb = *(const float4*)(b1 + col);
            const int of = w * 4096 + ml * 64 + (((mt * 2 + (q >> 1)) ^ ((ml >> 1) & 3)) * 16) + (q & 1) * 8;
            #pragma unroll
            for (int nt = 0; nt < 4; ++nt) {
                const float4 a = *(const float4*)(Ptab + (size_t)srw[nt] * 512 + col);
                const float4 b = *(const float4*)(Ptab + (size_t)rrw[nt] * 512 + 256 + col);
                float4 v;
                v.x = elu_f(a.x + b.x + bb.x);
                v.y = elu_f(a.y + b.y + bb.y);
                v.z = elu_f(a.z + b.z + bb.z);
                v.w = elu_f(a.w + b.w + bb.w);
                ushort4 o; o.x = f2bf(v.x); o.y = f2bf(v.y); o.z = f2bf(v.z); o.w = f2bf(v.w);
                *(ushort4*)(AG + of + nt * 1024) = o;
            }
        }
    }
    __syncthreads();

    f32x4 acc[2][4];
    #pragma unroll
    for (int mt = 0; mt < 2; ++mt)
        #pragma unroll
        for (int nt = 0; nt < 4; ++nt) acc[mt][nt] = (f32x4){0.f,0.f,0.f,0.f};

    GEMM_CORE64(WH, WL)

    #pragma unroll
    for (int mt = 0; mt < 2; ++mt) {
        const int col = w * 32 + mt * 16 + q * 4;
        const float4 bb = *(const float4*)(bias2 + col);
        #pragma unroll
        for (int nt = 0; nt < 4; ++nt) {
            const int row = bx * 64 + nt * 16 + ml;
            float4 v;
            v.x = elu_f(acc[mt][nt][0] + bb.x); v.y = elu_f(acc[mt][nt][1] + bb.y);
            v.z = elu_f(acc[mt][nt][2] + bb.z); v.w = elu_f(acc[mt][nt][3] + bb.w);
            ushort4 o; o.x = f2bf(v.x); o.y = f2bf(v.y); o.z = f2bf(v.z); o.w = f2bf(v.w);
            *(ushort4*)(C + (size_t)row * 256 + col) = o;
        }
    }
}

// ---------------------------------------------------------------------------
// Fused mlp4-L1(+node gather) -> mlp4-L2 -> MERGED dual LSTM-input GEMM.
// Units 1,2 as round 8; units 3+4 (fwd/rev Wih, independent readers of G2)
// merged via CORE_DUAL for 2x memory-level parallelism.
// ---------------------------------------------------------------------------
__global__ __launch_bounds__(512, 4)
void fused_m4(const us* __restrict__ Askip,
              const us* __restrict__ w4aH, const us* __restrict__ w4aL, const float* __restrict__ m4b1,
              const us* __restrict__ w4bH, const us* __restrict__ w4bL, const float* __restrict__ m4b2,
              const us* __restrict__ wfiH, const us* __restrict__ wfiL,
              const float* __restrict__ fbih, const float* __restrict__ fbhh,
              const us* __restrict__ wriH, const us* __restrict__ wriL,
              const float* __restrict__ rbih, const float* __restrict__ rbhh,
              const float* __restrict__ Ptab, const int* __restrict__ send, const int* __restrict__ recv,
              us* __restrict__ Gf, us* __restrict__ Gr)
{
    __shared__ char AG[32768];

    const int tid = threadIdx.x, lane = tid & 63, w = tid >> 6;  // 0..7
    const int ml = lane & 15, q = lane >> 4;
    const int lr = lane >> 2;
    const int cofs = (((lane & 3) ^ ((lane >> 3) & 3)) * 8);
    const int qs16 = (q ^ ((ml >> 1) & 3)) * 16;
    const int bx = blockIdx.x;

    int gtOf[2];
    #pragma unroll
    for (int mt = 0; mt < 2; ++mt)
        gtOf[mt] = w * 4096 + ml * 64 + (((mt * 2 + (q >> 1)) ^ ((ml >> 1) & 3)) * 16) + (q & 1) * 8;

    f32x4 acc[2][4];

    // A prologue: wave w stages k-slab w (4 groups)
    #pragma unroll
    for (int g = 0; g < 4; ++g)
        gld16(AG + w * 4096 + g * 1024,
              Askip + (size_t)(bx * 64 + g * 16 + lr) * 256 + w * 32 + cofs);
    __builtin_amdgcn_s_waitcnt(VM0);
    __syncthreads();

    ushort4 r16[2][4];

    // ---- unit 1: mlp4 layer-1 skip GEMM + node-table gather + elu ----
    #pragma unroll
    for (int mt = 0; mt < 2; ++mt)
        #pragma unroll
        for (int nt = 0; nt < 4; ++nt) acc[mt][nt] = (f32x4){0.f,0.f,0.f,0.f};
    GEMM_CORE64(w4aH, w4aL)
    {
        int srw[4], rrw[4];
        #pragma unroll
        for (int nt = 0; nt < 4; ++nt) {
            const int row = bx * 64 + nt * 16 + ml;
            const int t = row / E_;
            const int e = row - t * E_;
            srw[nt] = t * N_ + send[e];
            rrw[nt] = t * N_ + recv[e];
        }
        #pragma unroll
        for (int mt = 0; mt < 2; ++mt) {
            const int col = w * 32 + mt * 16 + q * 4;
            const float4 bb = *(const float4*)(m4b1 + col);
            #pragma unroll
            for (int nt = 0; nt < 4; ++nt) {
                float4 v;
                v.x = acc[mt][nt][0] + bb.x; v.y = acc[mt][nt][1] + bb.y;
                v.z = acc[mt][nt][2] + bb.z; v.w = acc[mt][nt][3] + bb.w;
                const float4 pS = *(const float4*)(Ptab + (size_t)srw[nt] * 512 + col);
                const float4 pR = *(const float4*)(Ptab + (size_t)rrw[nt] * 512 + 256 + col);
                v.x += pS.x + pR.x; v.y += pS.y + pR.y;
                v.z += pS.z + pR.z; v.w += pS.w + pR.w;
                v.x = elu_f(v.x); v.y = elu_f(v.y); v.z = elu_f(v.z); v.w = elu_f(v.w);
                ushort4 o; o.x = f2bf(v.x); o.y = f2bf(v.y); o.z = f2bf(v.z); o.w = f2bf(v.w);
                r16[mt][nt] = o;
            }
        }
    }
    __syncthreads();   // all waves done reading AG (A)
    #pragma unroll
    for (int mt = 0; mt < 2; ++mt)
        #pragma unroll
        for (int nt = 0; nt < 4; ++nt)
            *(ushort4*)(AG + gtOf[mt] + nt * 1024) = r16[mt][nt];
    __syncthreads();   // publish G1

    // ---- unit 2: mlp4 layer-2 ----
    #pragma unroll
    for (int mt = 0; mt < 2; ++mt)
        #pragma unroll
        for (int nt = 0; nt < 4; ++nt) acc[mt][nt] = (f32x4){0.f,0.f,0.f,0.f};
    GEMM_CORE64(w4bH, w4bL)
    #pragma unroll
    for (int mt = 0; mt < 2; ++mt) {
        const int col = w * 32 + mt * 16 + q * 4;
        const float4 bb = *(const float4*)(m4b2 + col);
        #pragma unroll
        for (int nt = 0; nt < 4; ++nt) {
            float4 v;
            v.x = elu_f(acc[mt][nt][0] + bb.x); v.y = elu_f(acc[mt][nt][1] + bb.y);
            v.z = elu_f(acc[mt][nt][2] + bb.z); v.w = elu_f(acc[mt][nt][3] + bb.w);
            ushort4 o; o.x = f2bf(v.x); o.y = f2bf(v.y); o.z = f2bf(v.z); o.w = f2bf(v.w);
            r16[mt][nt] = o;
        }
    }
    __syncthreads();   // all waves done reading G1
    #pragma unroll
    for (int mt = 0; mt < 2; ++mt)
        #pragma unroll
        for (int nt = 0; nt < 4; ++nt)
            *(ushort4*)(AG + gtOf[mt] + nt * 1024) = r16[mt][nt];
    __syncthreads();   // publish G2

    // ---- units 3+4 merged: forward + reverse Wih (independent, same G2) ----
    f32x4 accR[2][4];
    #pragma unroll
    for (int mt = 0; mt < 2; ++mt)
        #pragma unroll
        for (int nt = 0; nt < 4; ++nt) {
            acc[mt][nt]  = (f32x4){0.f,0.f,0.f,0.f};
            accR[mt][nt] = (f32x4){0.f,0.f,0.f,0.f};
        }
    CORE_DUAL(wfiH, wfiL, wriH, wriL)
    #pragma unroll
    for (int mt = 0; mt < 2; ++mt) {
        const int col = w * 32 + mt * 16 + q * 4;
        float4 bf = *(const float4*)(fbih + col);
        const float4 bf2 = *(const float4*)(fbhh + col);
        bf.x += bf2.x; bf.y += bf2.y; bf.z += bf2.z; bf.w += bf2.w;
        float4 br = *(const float4*)(rbih + col);
        const float4 br2 = *(const float4*)(rbhh + col);
        br.x += br2.x; br.y += br2.y; br.z += br2.z; br.w += br2.w;
        #pragma unroll
        for (int nt = 0; nt < 4; ++nt) {
            const int row = bx * 64 + nt * 16 + ml;
            float4 v;
            v.x = acc[mt][nt][0] + bf.x; v.y = acc[mt][nt][1] + bf.y;
            v.z = acc[mt][nt][2] + bf.z; v.w = acc[mt][nt][3] + bf.w;
            ushort4 o; o.x = f2bf(v.x); o.y = f2bf(v.y); o.z = f2bf(v.z); o.w = f2bf(v.w);
            *(ushort4*)(Gf + (size_t)row * 256 + col) = o;
            v.x = accR[mt][nt][0] + br.x; v.y = accR[mt][nt][1] + br.y;
            v.z = accR[mt][nt][2] + br.z; v.w = accR[mt][nt][3] + br.w;
            ushort4 o2; o2.x = f2bf(v.x); o2.y = f2bf(v.y); o2.z = f2bf(v.z); o2.w = f2bf(v.w);
            *(ushort4*)(Gr + (size_t)row * 256 + col) = o2;
        }
    }
}

template<bool DOELU, typename TA, typename TC>
__global__ __launch_bounds__(256)
void gemm_nt(const TA* __restrict__ A, const float* __restrict__ W,
             const float* __restrict__ bias1,
             TC* __restrict__ C, int M, int Kdim)
{
    __shared__ float As[16][64];
    __shared__ float Ws[16][64];

    const int tid = threadIdx.x;
    const int am  = tid >> 2;
    const int ak  = (tid & 3) * 4;
    const int gm  = blockIdx.x * 64 + am;

    const TA* aptr0 = A + (size_t)gm * Kdim;
    const float* wptr = W + (size_t)(blockIdx.y * 64 + am) * Kdim;

    const int tx = tid & 15, ty = tid >> 4;
    float acc[4][4] = {};

    for (int k0 = 0; k0 < Kdim; k0 += 16) {
        const float4 a4 = ld4f(aptr0 + k0 + ak);
        const float4 w4 = *(const float4*)(wptr + k0 + (tid & 3) * 4);

        __syncthreads();
        As[ak+0][am] = a4.x; As[ak+1][am] = a4.y; As[ak+2][am] = a4.z; As[ak+3][am] = a4.w;
        const int wk = (tid & 3) * 4;
        Ws[wk+0][am] = w4.x; Ws[wk+1][am] = w4.y; Ws[wk+2][am] = w4.z; Ws[wk+3][am] = w4.w;
        __syncthreads();

        #pragma unroll
        for (int kq = 0; kq < 16; ++kq) {
            const float4 av = *(const float4*)&As[kq][ty * 4];
            const float4 wv = *(const float4*)&Ws[kq][tx * 4];
            const float a_[4] = {av.x, av.y, av.z, av.w};
            const float w_[4] = {wv.x, wv.y, wv.z, wv.w};
            #pragma unroll
            for (int i = 0; i < 4; ++i)
                #pragma unroll
                for (int j = 0; j < 4; ++j)
                    acc[i][j] += a_[i] * w_[j];
        }
    }

    const int gn = blockIdx.y * 64 + tx * 4;
    const float4 bb = *(const float4*)&bias1[gn];
    #pragma unroll
    for (int i = 0; i < 4; ++i) {
        const int row = blockIdx.x * 64 + ty * 4 + i;
        float4 o;
        o.x = acc[i][0] + bb.x; o.y = acc[i][1] + bb.y;
        o.z = acc[i][2] + bb.z; o.w = acc[i][3] + bb.w;
        if (DOELU) { o.x = elu_f(o.x); o.y = elu_f(o.y); o.z = elu_f(o.z); o.w = elu_f(o.w); }
        st4f(C + (size_t)row * 256 + gn, o);
    }
}

// edge2node aggregate, analytic edge list (bit-identical summation order).
__global__ __launch_bounds__(256)
void aggregate_kernel(const us* __restrict__ eSkip, const int* __restrict__ recv,
                      float* __restrict__ nAgg)
{
    const int t = blockIdx.x / N_;
    const int j = blockIdx.x - t * N_;
    const int c = threadIdx.x;
    const us* basep = eSkip + (size_t)t * E_ * H_ + c;
    float acc = 0.f;
    #pragma unroll
    for (int s = 0; s < N_; ++s) {
        if (s == j) continue;
        const int e = s * (N_ - 1) + (j < s ? j : j - 1);
        acc += bf2f(basep[(size_t)e * H_]);
    }
    nAgg[(size_t)blockIdx.x * H_ + c] = acc;
}

// LSTM recurrence v4: wave = r-quarter, pointwise in registers, ping-pong h
// planes, one barrier/step. Bit-identical arithmetic.
__global__ __launch_bounds__(256)
void lstm_mfma(const us* __restrict__ Gf, const us* __restrict__ Gr,
               const us* __restrict__ fWhhH, const us* __restrict__ fWhhL,
               const us* __restrict__ rWhhH, const us* __restrict__ rWhhL,
               float* __restrict__ hsF, float* __restrict__ hsR)
{
    const int NBD = (E_ + 15) / 16;
    const bool revd = (int)blockIdx.x >= NBD;
    const int blk = revd ? (int)blockIdx.x - NBD : (int)blockIdx.x;
    const int e0 = blk * 16;
    const us* G  = revd ? Gr : Gf;
    const us* WH = revd ? rWhhH : fWhhH;
    const us* WL = revd ? rWhhL : fWhhL;
    float* hs    = revd ? hsR : hsF;

    const int tid  = threadIdx.x;
    const int lane = tid & 63;
    const int w    = tid >> 6;
    const int ml   = lane & 15;
    const int q    = lane >> 4;

    __shared__ us hHi[2][16][72];
    __shared__ us hLo[2][16][72];

    short8 wfh[4][2], wfl[4][2];
    #pragma unroll
    for (int mt = 0; mt < 4; ++mt) {
        const int row = mt * 64 + w * 16 + ml;
        #pragma unroll
        for (int ks = 0; ks < 2; ++ks) {
            wfh[mt][ks] = *(const short8*)(WH + (size_t)row * 64 + ks * 32 + q * 8);
            wfl[mt][ks] = *(const short8*)(WL + (size_t)row * 64 + ks * 32 + q * 8);
        }
    }

    for (int i = tid; i < 16 * 72; i += 256) { (&hHi[0][0][0])[i] = 0; (&hLo[0][0][0])[i] = 0; }

    const int eMF = min(e0 + ml, E_ - 1);
    const bool wr = (e0 + ml) < E_;
    const int gOfs = w * 16 + q * 4;
    float4 cst = make_float4(0.f, 0.f, 0.f, 0.f);

    ushort4 gcur[4], gnxt[4];
    {
        const int tt0 = revd ? (T_ - 1) : 0;
        const us* gp = G + ((size_t)tt0 * E_ + eMF) * 256 + gOfs;
        #pragma unroll
        for (int mt = 0; mt < 4; ++mt) gcur[mt] = *(const ushort4*)(gp + mt * 64);
    }
    __syncthreads();

    for (int s = 0; s < T_; ++s) {
        const int tt = revd ? (T_ - 1 - s) : s;
        {
            const int sn = (s + 1 < T_) ? s + 1 : s;
            const int tn = revd ? (T_ - 1 - sn) : sn;
            const us* gp = G + ((size_t)tn * E_ + eMF) * 256 + gOfs;
            #pragma unroll
            for (int mt = 0; mt < 4; ++mt) gnxt[mt] = *(const ushort4*)(gp + mt * 64);
        }
        const int rb = s & 1, wb = rb ^ 1;
        short8 bh[2], bl[2];
        #pragma unroll
        for (int ks = 0; ks < 2; ++ks) {
            bh[ks] = *(const short8*)(&hHi[rb][ml][ks * 32 + q * 8]);
            bl[ks] = *(const short8*)(&hLo[rb][ml][ks * 32 + q * 8]);
        }
        f32x4 acc[4];
        #pragma unroll
        for (int mt = 0; mt < 4; ++mt) {
            acc[mt][0] = bf2f(gcur[mt].x); acc[mt][1] = bf2f(gcur[mt].y);
            acc[mt][2] = bf2f(gcur[mt].z); acc[mt][3] = bf2f(gcur[mt].w);
            #pragma unroll
            for (int ks = 0; ks < 2; ++ks) {
                acc[mt] = __builtin_amdgcn_mfma_f32_16x16x32_bf16(wfh[mt][ks], bh[ks], acc[mt], 0, 0, 0);
                acc[mt] = __builtin_amdgcn_mfma_f32_16x16x32_bf16(wfh[mt][ks], bl[ks], acc[mt], 0, 0, 0);
                acc[mt] = __builtin_amdgcn_mfma_f32_16x16x32_bf16(wfl[mt][ks], bh[ks], acc[mt], 0, 0, 0);
            }
        }
        float4 hv;
        cst.x = sig_f(acc[1][0])*cst.x + sig_f(acc[0][0])*tanh_f(acc[2][0]); hv.x = sig_f(acc[3][0])*tanh_f(cst.x);
        cst.y = sig_f(acc[1][1])*cst.y + sig_f(acc[0][1])*tanh_f(acc[2][1]); hv.y = sig_f(acc[3][1])*tanh_f(cst.y);
        cst.z = sig_f(acc[1][2])*cst.z + sig_f(acc[0][2])*tanh_f(acc[2][2]); hv.z = sig_f(acc[3][2])*tanh_f(cst.z);
        cst.w = sig_f(acc[1][3])*cst.w + sig_f(acc[0][3])*tanh_f(acc[2][3]); hv.w = sig_f(acc[3][3])*tanh_f(cst.w);
        ushort4 hh4, hl4;
        hh4.x = f2bf(hv.x); hl4.x = f2bf(hv.x - bf2f(hh4.x));
        hh4.y = f2bf(hv.y); hl4.y = f2bf(hv.y - bf2f(hh4.y));
        hh4.z = f2bf(hv.z); hl4.z = f2bf(hv.z - bf2f(hh4.z));
        hh4.w = f2bf(hv.w); hl4.w = f2bf(hv.w - bf2f(hh4.w));
        *(ushort4*)(&hHi[wb][ml][gOfs]) = hh4;
        *(ushort4*)(&hLo[wb][ml][gOfs]) = hl4;
        if (wr)
            *(float4*)(&hs[((size_t)tt * E_ + e0 + ml) * 64 + gOfs]) = hv;
        __syncthreads();
        #pragma unroll
        for (int mt = 0; mt < 4; ++mt) gcur[mt] = gnxt[mt];
    }
}

__global__ __launch_bounds__(256)
void out_kernel(const float* __restrict__ hsF, const float* __restrict__ hsR,
                const float* __restrict__ priW, const float* __restrict__ prib,
                const float* __restrict__ encW, const float* __restrict__ encb,
                float* __restrict__ out)
{
    const int idx = blockIdx.x * 256 + threadIdx.x;
    const float* f = hsF + (size_t)idx * 64;
    const float* r = hsR + (size_t)idx * 64;
    float p0 = prib[0], p1 = prib[1], q0 = encb[0], q1 = encb[1];
    #pragma unroll
    for (int k4 = 0; k4 < 16; ++k4) {
        const float4 fv = *(const float4*)(f + k4 * 4);
        const float4 rv = *(const float4*)(r + k4 * 4);
        p0 += dot4(fv, *(const float4*)(priW + k4 * 4));
        p1 += dot4(fv, *(const float4*)(priW + 64 + k4 * 4));
        q0 += dot4(fv, *(const float4*)(encW + k4 * 4))
            + dot4(rv, *(const float4*)(encW + 64 + k4 * 4));
        q1 += dot4(fv, *(const float4*)(encW + 128 + k4 * 4))
            + dot4(rv, *(const float4*)(encW + 192 + k4 * 4));
    }
    float4 o; o.x = p0; o.y = p1; o.z = q0; o.w = q1;
    *(float4*)(out + (size_t)idx * 4) = o;
}

extern "C" void kernel_launch(void* const* d_in, const int* in_sizes, int n_in,
                              void* d_out, int out_size, void* d_ws, size_t ws_size,
                              hipStream_t stream)
{
    const float* x    = (const float*)d_in[0];
    const int*   send = (const int*)d_in[2];
    const int*   recv = (const int*)d_in[3];
    const float* m1W1 = (const float*)d_in[4];  const float* m1b1 = (const float*)d_in[5];
    const float* m1W2 = (const float*)d_in[6];  const float* m1b2 = (const float*)d_in[7];
    const float* m2W1 = (const float*)d_in[8];  const float* m2b1 = (const float*)d_in[9];
    const float* m2W2 = (const float*)d_in[10]; const float* m2b2 = (const float*)d_in[11];
    const float* m3W1 = (const float*)d_in[12]; const float* m3b1 = (const float*)d_in[13];
    const float* m3W2 = (const float*)d_in[14]; const float* m3b2 = (const float*)d_in[15];
    const float* m4W1 = (const float*)d_in[16]; const float* m4b1 = (const float*)d_in[17];
    const float* m4W2 = (const float*)d_in[18]; const float* m4b2 = (const float*)d_in[19];
    const float* fWih = (const float*)d_in[20]; const float* fWhh = (const float*)d_in[21];
    const float* fbih = (const float*)d_in[22]; const float* fbhh = (const float*)d_in[23];
    const float* rWih = (const float*)d_in[24]; const float* rWhh = (const float*)d_in[25];
    const float* rbih = (const float*)d_in[26]; const float* rbhh = (const float*)d_in[27];
    const float* encW = (const float*)d_in[28]; const float* encb = (const float*)d_in[29];
    const float* priW = (const float*)d_in[30]; const float* prib = (const float*)d_in[31];

    const size_t SZN  = (size_t)TN_ * H_;
    const size_t SZE  = (size_t)TE_ * H_;
    // Ptab (TN x 512 f32) overlays n_agg+m3t exactly (both TN*2048 bytes).
    float* n_agg = (float*)d_ws;
    float* m3t   = n_agg + SZN;
    float* Ptab  = (float*)d_ws;
    us* h16      = (us*)(m3t + SZN);
    us* n3       = h16 + SZN;
    us* w2bH = n3  + SZN;          us* w2bL = w2bH + 65536;
    us* w4aH = w2bL + 65536;       us* w4aL = w4aH + 65536;
    us* w4bH = w4aL + 65536;       us* w4bL = w4bH + 65536;
    us* wfiH = w4bL + 65536;       us* wfiL = wfiH + 65536;
    us* wriH = wfiL + 65536;       us* wriL = wriH + 65536;
    us* whfH = wriL + 65536;       us* whfL = whfH + 16384;
    us* whrH = whfL + 16384;       us* whrL = whrH + 16384;
    us* bufA16 = whrL + 16384;
    us* bufB16 = bufA16 + SZE;
    us* bufC16 = bufB16 + SZE;
    float* hsF = (float*)bufC16;
    float* hsR = hsF + (size_t)TE_ * R_;
    const size_t needed = ((size_t)(bufC16 + SZE) - (size_t)d_ws);
    if (ws_size < needed) return;

    const dim3 gN(TN_ / 64, 4), gNP(TN_ / 64, 8);

    wsplit_all<<<1408, 256, 0, stream>>>(m2W2, w2bH, w2bL,
                                         m4W1, w4aH, w4aL,   // packed, strided: cols 512..767
                                         m4W2, w4bH, w4bL,
                                         fWih, wfiH, wfiL, rWih, wriH, wriL,
                                         fWhh, whfH, whfL, rWhh, whrH, whrL);

    mlp1_kernel<<<TN_ / 8, 256, 0, stream>>>(x, m1W1, m1b1, m1W2, m1b2, h16);
    // mlp2 layer 1 via node factorization
    node_proj<<<gNP, 256, 0, stream>>>(h16, m2W1, 512, Ptab);
    // mlp2 layer 2 with fused edge gather (reads Ptab directly)
    gemm_bf<<<TE_ / 64, 512, 0, stream>>>(Ptab, m2b1, send, recv, w2bH, w2bL, m2b2, bufB16);
    aggregate_kernel<<<TN_, 256, 0, stream>>>(bufB16, recv, n_agg);
    gemm_nt<true, float, float><<<gN, 256, 0, stream>>>(n_agg, m3W1, m3b1, m3t, TN_, 256);
    gemm_nt<true, float, us><<<gN, 256, 0, stream>>>(m3t, m3W2, m3b2, n3, TN_, 256);
    // mlp4 node parts
    node_proj<<<gNP, 256, 0, stream>>>(n3, m4W1, 768, Ptab);
    // fused: mlp4-L1(skip GEMM + gather) -> mlp4-L2 -> merged dual LSTM-input GEMM
    fused_m4<<<TE_ / 64, 512, 0, stream>>>(bufB16,
                                           w4aH, w4aL, m4b1,
                                           w4bH, w4bL, m4b2,
                                           wfiH, wfiL, fbih, fbhh,
                                           wriH, wriL, rbih, rbhh,
                                           Ptab, send, recv, bufA16, bufB16);
    lstm_mfma<<<2 * ((E_ + 15) / 16), 256, 0, stream>>>(bufA16, bufB16, whfH, whfL, whrH, whrL, hsF, hsR);
    out_kernel<<<TE_ / 256, 256, 0, stream>>>(hsF, hsR, priW, prib, encW, encb, (float*)d_out);
}

// Round 13
// 495.001 us; speedup vs baseline: 1.0793x; 1.0793x over previous
//
#include <hip/hip_runtime.h>
#include <math.h>

#define T_ 64
#define N_ 40
#define D_ 4
#define H_ 256
#define R_ 64
#define E_ 1560
#define TE_ (T_*E_)
#define TN_ (T_*N_)

typedef unsigned short us;
typedef short short8 __attribute__((ext_vector_type(8)));
typedef float f32x4 __attribute__((ext_vector_type(4)));

__device__ __forceinline__ float elu_f(float x){ return x > 0.f ? x : (__expf(x) - 1.f); }
__device__ __forceinline__ float sig_f(float x){ return 1.f/(1.f+__expf(-x)); }
__device__ __forceinline__ float tanh_f(float x){ return 2.f/(1.f+__expf(-2.f*x)) - 1.f; }
__device__ __forceinline__ float dot4(float4 a, float4 b){ return a.x*b.x + a.y*b.y + a.z*b.z + a.w*b.w; }

__device__ __forceinline__ float bf2f(us u){ return __uint_as_float(((unsigned int)u) << 16); }
__device__ __forceinline__ us f2bf(float f){
    unsigned int u = __float_as_uint(f);
    u += 0x7FFFu + ((u >> 16) & 1u);
    return (us)(u >> 16);
}
__device__ __forceinline__ float4 ld4f(const float* p){ return *(const float4*)p; }
__device__ __forceinline__ float4 ld4f(const us* p){
    ushort4 v = *(const ushort4*)p;
    return make_float4(bf2f(v.x), bf2f(v.y), bf2f(v.z), bf2f(v.w));
}
__device__ __forceinline__ void st4f(float* p, float4 v){ *(float4*)p = v; }
__device__ __forceinline__ void st4f(us* p, float4 v){
    ushort4 o; o.x = f2bf(v.x); o.y = f2bf(v.y); o.z = f2bf(v.z); o.w = f2bf(v.w);
    *(ushort4*)p = o;
}

__device__ __forceinline__ void gld16(void* lds, const void* g){
    __builtin_amdgcn_global_load_lds((const __attribute__((address_space(1))) unsigned int*)g,
                                     (__attribute__((address_space(3))) unsigned int*)lds,
                                     16, 0, 0);
}

__device__ __forceinline__ void wsplit1(const float* W, us* hi, us* lo, int i){
    const float w = W[i];
    const us h = f2bf(w);
    hi[i] = h;
    lo[i] = f2bf(w - bf2f(h));
}

// Fragment-contiguous W' packing for the reg-W GEMM core.
// Dest index i = fh*8192 + k*1024 + mt*512 + lane*8 + jj holds
// W[R*stride + colOff + K], R = fh*32 + mt*16 + (lane&15),
// K = k*32 + (lane>>4)*8 + jj -> per-(k,mt) fragment load is coalesced.
__device__ __forceinline__ void wsplitF(const float* __restrict__ W, int stride, int colOff,
                                        us* hi, us* lo, int i){
    const int jj   = i & 7;
    const int lane = (i >> 3) & 63;
    const int mt   = (i >> 9) & 1;
    const int k    = (i >> 10) & 7;
    const int fh   = i >> 13;
    const int R = fh * 32 + mt * 16 + (lane & 15);
    const int K = k * 32 + (lane >> 4) * 8 + jj;
    const float w = W[(size_t)R * stride + colOff + K];
    const us h = f2bf(w);
    hi[i] = h;
    lo[i] = f2bf(w - bf2f(h));
}

// 5 packed GEMM weights + 2 linear LSTM Whh splits.
__global__ __launch_bounds__(256)
void wsplit_all(const float* __restrict__ s0, us* h0, us* l0,
                const float* __restrict__ s1, us* h1, us* l1,
                const float* __restrict__ s2, us* h2, us* l2,
                const float* __restrict__ s3, us* h3, us* l3,
                const float* __restrict__ s4, us* h4, us* l4,
                const float* __restrict__ s5, us* h5, us* l5,
                const float* __restrict__ s6, us* h6, us* l6)
{
    int i = blockIdx.x * 256 + threadIdx.x;
    if (i < 65536) { wsplitF(s0, 256,   0, h0, l0, i); return; } i -= 65536;
    if (i < 65536) { wsplitF(s1, 768, 512, h1, l1, i); return; } i -= 65536;
    if (i < 65536) { wsplitF(s2, 256,   0, h2, l2, i); return; } i -= 65536;
    if (i < 65536) { wsplitF(s3, 256,   0, h3, l3, i); return; } i -= 65536;
    if (i < 65536) { wsplitF(s4, 256,   0, h4, l4, i); return; } i -= 65536;
    if (i < 16384) { wsplit1(s5, h5, l5, i); return; } i -= 16384;
    wsplit1(s6, h6, l6, i);
}

__global__ __launch_bounds__(256)
void mlp1_kernel(const float* __restrict__ x,
                 const float* __restrict__ W1, const float* __restrict__ b1,
                 const float* __restrict__ W2, const float* __restrict__ b2,
                 us* __restrict__ hout)
{
    __shared__ float xs[8][4];
    __shared__ float h1[8][256];
    const int tid = threadIdx.x;
    const int r0  = blockIdx.x * 8;

    if (tid < 32) xs[tid >> 2][tid & 3] = x[r0 * 4 + tid];
    __syncthreads();

    const float4 w1 = *(const float4*)&W1[tid * 4];
    const float bb1 = b1[tid];
    #pragma unroll
    for (int row = 0; row < 8; ++row) {
        float v = bb1 + xs[row][0]*w1.x + xs[row][1]*w1.y + xs[row][2]*w1.z + xs[row][3]*w1.w;
        h1[row][tid] = elu_f(v);
    }
    __syncthreads();

    float acc[8];
    const float bb2 = b2[tid];
    #pragma unroll
    for (int row = 0; row < 8; ++row) acc[row] = bb2;
    const float* w2row = W2 + (size_t)tid * 256;
    for (int k4 = 0; k4 < 64; ++k4) {
        const float4 w = *(const float4*)&w2row[k4 * 4];
        #pragma unroll
        for (int row = 0; row < 8; ++row) {
            const float4 hh = *(const float4*)&h1[row][k4 * 4];
            acc[row] += dot4(hh, w);
        }
    }
    #pragma unroll
    for (int row = 0; row < 8; ++row)
        hout[(size_t)(r0 + row) * 256 + tid] = f2bf(elu_f(acc[row]));
}

// ---------------------------------------------------------------------------
// Node-level projection: P[n, part*256 + j] = sum_k A[n,k] * W[j, part*256+k]
// ---------------------------------------------------------------------------
__global__ __launch_bounds__(256)
void node_proj(const us* __restrict__ A, const float* __restrict__ W,
               int wstride, float* __restrict__ P)
{
    __shared__ float As[16][64];
    __shared__ float Ws[16][64];

    const int tid  = threadIdx.x;
    const int am   = tid >> 2;
    const int gm   = blockIdx.x * 64 + am;
    const int part = blockIdx.y >> 2;
    const int wq   = blockIdx.y & 3;

    const us* aptr = A + (size_t)gm * 256;
    const float* wptr = W + (size_t)(wq * 64 + am) * wstride + part * 256;

    const int tx = tid & 15, ty = tid >> 4;
    float acc[4][4] = {};

    for (int k0 = 0; k0 < 256; k0 += 16) {
        const float4 a4 = ld4f(aptr + k0 + (tid & 3) * 4);
        const float4 w4 = *(const float4*)(wptr + k0 + (tid & 3) * 4);

        __syncthreads();
        const int ak = (tid & 3) * 4;
        As[ak+0][am] = a4.x; As[ak+1][am] = a4.y; As[ak+2][am] = a4.z; As[ak+3][am] = a4.w;
        Ws[ak+0][am] = w4.x; Ws[ak+1][am] = w4.y; Ws[ak+2][am] = w4.z; Ws[ak+3][am] = w4.w;
        __syncthreads();

        #pragma unroll
        for (int kq = 0; kq < 16; ++kq) {
            const float4 av = *(const float4*)&As[kq][ty * 4];
            const float4 wv = *(const float4*)&Ws[kq][tx * 4];
            const float a_[4] = {av.x, av.y, av.z, av.w};
            const float w_[4] = {wv.x, wv.y, wv.z, wv.w};
            #pragma unroll
            for (int i = 0; i < 4; ++i)
                #pragma unroll
                for (int j = 0; j < 4; ++j)
                    acc[i][j] += a_[i] * w_[j];
        }
    }

    const int gn = part * 256 + wq * 64 + tx * 4;
    #pragma unroll
    for (int i = 0; i < 4; ++i) {
        const int row = blockIdx.x * 64 + ty * 4 + i;
        float4 o;
        o.x = acc[i][0]; o.y = acc[i][1]; o.z = acc[i][2]; o.w = acc[i][3];
        *(float4*)(P + (size_t)row * 512 + gn) = o;
    }
}

// ---------------------------------------------------------------------------
// Round-20 GEMM core (VERIFIED BEST, round 8/11): 64-row tiles, 512 threads
// (8 waves), launch_bounds(512,4) -> VGPR cap 128, compiler settles at 64,
// no spill; 32KB LDS -> up to 4 blocks/CU co-resident. Latency hiding is
// TLP. LDS = A panel only (8 k-slabs x 4 groups x 1KB). Wave w owns
// out-cols w*32..+31; W fragments from packed W' (coalesced, L2-resident).
// Design-space notes (all measured, all worse): 2-panel W-reuse loses TLP
// (r10, 159us); dual-stream ILP spills (r12, 191us, WRITE 276MB); ILP
// prefetch impossible under VGPR wall (r5/r6); (512,8) bound spills (r7);
// node-chain fusion loses grid parallelism (r9). This config is the
// constrained optimum of the structure. Accumulation order per output
// element: k asc, hi then lo -> bit-identical to reference path.
// ---------------------------------------------------------------------------
#define VM0   0x3F70   // s_waitcnt vmcnt(0)

#define GEMM_CORE64(WHp, WLp)                                                            \
    {                                                                                    \
        const us* wbh = (WHp) + w * 8192 + lane * 8;                                     \
        const us* wbl = (WLp) + w * 8192 + lane * 8;                                     \
        _Pragma("unroll")                                                                \
        for (int k = 0; k < 8; ++k) {                                                    \
            short8 wh[2], wl[2], ef[4];                                                  \
            _Pragma("unroll")                                                            \
            for (int mt = 0; mt < 2; ++mt) {                                             \
                wh[mt] = *(const short8*)(wbh + (k * 2 + mt) * 512);                     \
                wl[mt] = *(const short8*)(wbl + (k * 2 + mt) * 512);                     \
            }                                                                            \
            _Pragma("unroll")                                                            \
            for (int nt = 0; nt < 4; ++nt)                                               \
                ef[nt] = *(const short8*)(AG + k * 4096 + nt * 1024 + ml * 64 + qs16);   \
            __builtin_amdgcn_s_setprio(1);                                               \
            _Pragma("unroll")                                                            \
            for (int nt = 0; nt < 4; ++nt)                                               \
                _Pragma("unroll")                                                        \
                for (int mt = 0; mt < 2; ++mt) {                                         \
                    acc[mt][nt] = __builtin_amdgcn_mfma_f32_16x16x32_bf16(               \
                        wh[mt], ef[nt], acc[mt][nt], 0, 0, 0);                           \
                    acc[mt][nt] = __builtin_amdgcn_mfma_f32_16x16x32_bf16(               \
                        wl[mt], ef[nt], acc[mt][nt], 0, 0, 0);                           \
                }                                                                        \
            __builtin_amdgcn_s_setprio(0);                                               \
        }                                                                                \
    }

// mlp2 layer 2 with the edge gather+elu FUSED into the A-panel prologue:
// A[row,col] = elu(P[send]+P[recv,+256]+b1) computed in-register and written
// bf16 to the swizzled LDS panel. Replaces edge_gather_elu + the bufA16 HBM
// round-trip. Correctness verified rounds 7-12 (absmax unchanged).
__global__ __launch_bounds__(512, 4)
void gemm_bf(const float* __restrict__ Ptab, const float* __restrict__ b1,
             const int* __restrict__ send, const int* __restrict__ recv,
             const us* __restrict__ WH, const us* __restrict__ WL,
             const float* __restrict__ bias2, us* __restrict__ C)
{
    __shared__ char AG[32768];

    const int tid = threadIdx.x, lane = tid & 63, w = tid >> 6;  // w 0..7
    const int ml = lane & 15, q = lane >> 4;
    const int qs16 = (q ^ ((ml >> 1) & 3)) * 16;
    const int bx = blockIdx.x;

    // prologue: gather + elu + pack into swizzled A panel
    {
        int srw[4], rrw[4];
        #pragma unroll
        for (int nt = 0; nt < 4; ++nt) {
            const int row = bx * 64 + nt * 16 + ml;
            const int t = row / E_;
            const int e = row - t * E_;
            srw[nt] = t * N_ + send[e];
            rrw[nt] = t * N_ + recv[e];
        }
        #pragma unroll
        for (int mt = 0; mt < 2; ++mt) {
            const int col = w * 32 + mt * 16 + q * 4;
            const float4 bb = *(const float4*)(b1 + col);
            const int of = w * 4096 + ml * 64 + (((mt * 2 + (q >> 1)) ^ ((ml >> 1) & 3)) * 16) + (q & 1) * 8;
            #pragma unroll
            for (int nt = 0; nt < 4; ++nt) {
                const float4 a = *(const float4*)(Ptab + (size_t)srw[nt] * 512 + col);
                const float4 b = *(const float4*)(Ptab + (size_t)rrw[nt] * 512 + 256 + col);
                float4 v;
                v.x = elu_f(a.x + b.x + bb.x);
                v.y = elu_f(a.y + b.y + bb.y);
                v.z = elu_f(a.z + b.z + bb.z);
                v.w = elu_f(a.w + b.w + bb.w);
                ushort4 o; o.x = f2bf(v.x); o.y = f2bf(v.y); o.z = f2bf(v.z); o.w = f2bf(v.w);
                *(ushort4*)(AG + of + nt * 1024) = o;
            }
        }
    }
    __syncthreads();

    f32x4 acc[2][4];
    #pragma unroll
    for (int mt = 0; mt < 2; ++mt)
        #pragma unroll
        for (int nt = 0; nt < 4; ++nt) acc[mt][nt] = (f32x4){0.f,0.f,0.f,0.f};

    GEMM_CORE64(WH, WL)

    #pragma unroll
    for (int mt = 0; mt < 2; ++mt) {
        const int col = w * 32 + mt * 16 + q * 4;
        const float4 bb = *(const float4*)(bias2 + col);
        #pragma unroll
        for (int nt = 0; nt < 4; ++nt) {
            const int row = bx * 64 + nt * 16 + ml;
            float4 v;
            v.x = elu_f(acc[mt][nt][0] + bb.x); v.y = elu_f(acc[mt][nt][1] + bb.y);
            v.z = elu_f(acc[mt][nt][2] + bb.z); v.w = elu_f(acc[mt][nt][3] + bb.w);
            ushort4 o; o.x = f2bf(v.x); o.y = f2bf(v.y); o.z = f2bf(v.z); o.w = f2bf(v.w);
            *(ushort4*)(C + (size_t)row * 256 + col) = o;
        }
    }
}

// ---------------------------------------------------------------------------
// Fused mlp4-L1(+node gather) -> mlp4-L2 -> dual LSTM-input GEMM.
// 64-row tiles, round-8 verified config; intermediate lives in AG
// (A -> G1 -> G2 in place, syncthreads-guarded).
// ---------------------------------------------------------------------------
__global__ __launch_bounds__(512, 4)
void fused_m4(const us* __restrict__ Askip,
              const us* __restrict__ w4aH, const us* __restrict__ w4aL, const float* __restrict__ m4b1,
              const us* __restrict__ w4bH, const us* __restrict__ w4bL, const float* __restrict__ m4b2,
              const us* __restrict__ wfiH, const us* __restrict__ wfiL,
              const float* __restrict__ fbih, const float* __restrict__ fbhh,
              const us* __restrict__ wriH, const us* __restrict__ wriL,
              const float* __restrict__ rbih, const float* __restrict__ rbhh,
              const float* __restrict__ Ptab, const int* __restrict__ send, const int* __restrict__ recv,
              us* __restrict__ Gf, us* __restrict__ Gr)
{
    __shared__ char AG[32768];

    const int tid = threadIdx.x, lane = tid & 63, w = tid >> 6;  // 0..7
    const int ml = lane & 15, q = lane >> 4;
    const int lr = lane >> 2;
    const int cofs = (((lane & 3) ^ ((lane >> 3) & 3)) * 8);
    const int qs16 = (q ^ ((ml >> 1) & 3)) * 16;
    const int bx = blockIdx.x;

    int gtOf[2];
    #pragma unroll
    for (int mt = 0; mt < 2; ++mt)
        gtOf[mt] = w * 4096 + ml * 64 + (((mt * 2 + (q >> 1)) ^ ((ml >> 1) & 3)) * 16) + (q & 1) * 8;

    f32x4 acc[2][4];

    // A prologue: wave w stages k-slab w (4 groups)
    #pragma unroll
    for (int g = 0; g < 4; ++g)
        gld16(AG + w * 4096 + g * 1024,
              Askip + (size_t)(bx * 64 + g * 16 + lr) * 256 + w * 32 + cofs);
    __builtin_amdgcn_s_waitcnt(VM0);
    __syncthreads();

    ushort4 r16[2][4];

    // ---- unit 1: mlp4 layer-1 skip GEMM + node-table gather + elu ----
    #pragma unroll
    for (int mt = 0; mt < 2; ++mt)
        #pragma unroll
        for (int nt = 0; nt < 4; ++nt) acc[mt][nt] = (f32x4){0.f,0.f,0.f,0.f};
    GEMM_CORE64(w4aH, w4aL)
    {
        int srw[4], rrw[4];
        #pragma unroll
        for (int nt = 0; nt < 4; ++nt) {
            const int row = bx * 64 + nt * 16 + ml;
            const int t = row / E_;
            const int e = row - t * E_;
            srw[nt] = t * N_ + send[e];
            rrw[nt] = t * N_ + recv[e];
        }
        #pragma unroll
        for (int mt = 0; mt < 2; ++mt) {
            const int col = w * 32 + mt * 16 + q * 4;
            const float4 bb = *(const float4*)(m4b1 + col);
            #pragma unroll
            for (int nt = 0; nt < 4; ++nt) {
                float4 v;
                v.x = acc[mt][nt][0] + bb.x; v.y = acc[mt][nt][1] + bb.y;
                v.z = acc[mt][nt][2] + bb.z; v.w = acc[mt][nt][3] + bb.w;
                const float4 pS = *(const float4*)(Ptab + (size_t)srw[nt] * 512 + col);
                const float4 pR = *(const float4*)(Ptab + (size_t)rrw[nt] * 512 + 256 + col);
                v.x += pS.x + pR.x; v.y += pS.y + pR.y;
                v.z += pS.z + pR.z; v.w += pS.w + pR.w;
                v.x = elu_f(v.x); v.y = elu_f(v.y); v.z = elu_f(v.z); v.w = elu_f(v.w);
                ushort4 o; o.x = f2bf(v.x); o.y = f2bf(v.y); o.z = f2bf(v.z); o.w = f2bf(v.w);
                r16[mt][nt] = o;
            }
        }
    }
    __syncthreads();   // all waves done reading AG (A)
    #pragma unroll
    for (int mt = 0; mt < 2; ++mt)
        #pragma unroll
        for (int nt = 0; nt < 4; ++nt)
            *(ushort4*)(AG + gtOf[mt] + nt * 1024) = r16[mt][nt];
    __syncthreads();   // publish G1

    // ---- unit 2: mlp4 layer-2 ----
    #pragma unroll
    for (int mt = 0; mt < 2; ++mt)
        #pragma unroll
        for (int nt = 0; nt < 4; ++nt) acc[mt][nt] = (f32x4){0.f,0.f,0.f,0.f};
    GEMM_CORE64(w4bH, w4bL)
    #pragma unroll
    for (int mt = 0; mt < 2; ++mt) {
        const int col = w * 32 + mt * 16 + q * 4;
        const float4 bb = *(const float4*)(m4b2 + col);
        #pragma unroll
        for (int nt = 0; nt < 4; ++nt) {
            float4 v;
            v.x = elu_f(acc[mt][nt][0] + bb.x); v.y = elu_f(acc[mt][nt][1] + bb.y);
            v.z = elu_f(acc[mt][nt][2] + bb.z); v.w = elu_f(acc[mt][nt][3] + bb.w);
            ushort4 o; o.x = f2bf(v.x); o.y = f2bf(v.y); o.z = f2bf(v.z); o.w = f2bf(v.w);
            r16[mt][nt] = o;
        }
    }
    __syncthreads();   // all waves done reading G1
    #pragma unroll
    for (int mt = 0; mt < 2; ++mt)
        #pragma unroll
        for (int nt = 0; nt < 4; ++nt)
            *(ushort4*)(AG + gtOf[mt] + nt * 1024) = r16[mt][nt];
    __syncthreads();   // publish G2

    // ---- unit 3: forward Wih ----
    #pragma unroll
    for (int mt = 0; mt < 2; ++mt)
        #pragma unroll
        for (int nt = 0; nt < 4; ++nt) acc[mt][nt] = (f32x4){0.f,0.f,0.f,0.f};
    GEMM_CORE64(wfiH, wfiL)
    #pragma unroll
    for (int mt = 0; mt < 2; ++mt) {
        const int col = w * 32 + mt * 16 + q * 4;
        float4 bb = *(const float4*)(fbih + col);
        const float4 b2 = *(const float4*)(fbhh + col);
        bb.x += b2.x; bb.y += b2.y; bb.z += b2.z; bb.w += b2.w;
        #pragma unroll
        for (int nt = 0; nt < 4; ++nt) {
            const int row = bx * 64 + nt * 16 + ml;
            float4 v;
            v.x = acc[mt][nt][0] + bb.x; v.y = acc[mt][nt][1] + bb.y;
            v.z = acc[mt][nt][2] + bb.z; v.w = acc[mt][nt][3] + bb.w;
            ushort4 o; o.x = f2bf(v.x); o.y = f2bf(v.y); o.z = f2bf(v.z); o.w = f2bf(v.w);
            *(ushort4*)(Gf + (size_t)row * 256 + col) = o;
        }
    }

    // ---- unit 4: reverse Wih ----
    #pragma unroll
    for (int mt = 0; mt < 2; ++mt)
        #pragma unroll
        for (int nt = 0; nt < 4; ++nt) acc[mt][nt] = (f32x4){0.f,0.f,0.f,0.f};
    GEMM_CORE64(wriH, wriL)
    #pragma unroll
    for (int mt = 0; mt < 2; ++mt) {
        const int col = w * 32 + mt * 16 + q * 4;
        float4 bb = *(const float4*)(rbih + col);
        const float4 b2 = *(const float4*)(rbhh + col);
        bb.x += b2.x; bb.y += b2.y; bb.z += b2.z; bb.w += b2.w;
        #pragma unroll
        for (int nt = 0; nt < 4; ++nt) {
            const int row = bx * 64 + nt * 16 + ml;
            float4 v;
            v.x = acc[mt][nt][0] + bb.x; v.y = acc[mt][nt][1] + bb.y;
            v.z = acc[mt][nt][2] + bb.z; v.w = acc[mt][nt][3] + bb.w;
            ushort4 o; o.x = f2bf(v.x); o.y = f2bf(v.y); o.z = f2bf(v.z); o.w = f2bf(v.w);
            *(ushort4*)(Gr + (size_t)row * 256 + col) = o;
        }
    }
}

template<bool DOELU, typename TA, typename TC>
__global__ __launch_bounds__(256)
void gemm_nt(const TA* __restrict__ A, const float* __restrict__ W,
             const float* __restrict__ bias1,
             TC* __restrict__ C, int M, int Kdim)
{
    __shared__ float As[16][64];
    __shared__ float Ws[16][64];

    const int tid = threadIdx.x;
    const int am  = tid >> 2;
    const int ak  = (tid & 3) * 4;
    const int gm  = blockIdx.x * 64 + am;

    const TA* aptr0 = A + (size_t)gm * Kdim;
    const float* wptr = W + (size_t)(blockIdx.y * 64 + am) * Kdim;

    const int tx = tid & 15, ty = tid >> 4;
    float acc[4][4] = {};

    for (int k0 = 0; k0 < Kdim; k0 += 16) {
        const float4 a4 = ld4f(aptr0 + k0 + ak);
        const float4 w4 = *(const float4*)(wptr + k0 + (tid & 3) * 4);

        __syncthreads();
        As[ak+0][am] = a4.x; As[ak+1][am] = a4.y; As[ak+2][am] = a4.z; As[ak+3][am] = a4.w;
        const int wk = (tid & 3) * 4;
        Ws[wk+0][am] = w4.x; Ws[wk+1][am] = w4.y; Ws[wk+2][am] = w4.z; Ws[wk+3][am] = w4.w;
        __syncthreads();

        #pragma unroll
        for (int kq = 0; kq < 16; ++kq) {
            const float4 av = *(const float4*)&As[kq][ty * 4];
            const float4 wv = *(const float4*)&Ws[kq][tx * 4];
            const float a_[4] = {av.x, av.y, av.z, av.w};
            const float w_[4] = {wv.x, wv.y, wv.z, wv.w};
            #pragma unroll
            for (int i = 0; i < 4; ++i)
                #pragma unroll
                for (int j = 0; j < 4; ++j)
                    acc[i][j] += a_[i] * w_[j];
        }
    }

    const int gn = blockIdx.y * 64 + tx * 4;
    const float4 bb = *(const float4*)&bias1[gn];
    #pragma unroll
    for (int i = 0; i < 4; ++i) {
        const int row = blockIdx.x * 64 + ty * 4 + i;
        float4 o;
        o.x = acc[i][0] + bb.x; o.y = acc[i][1] + bb.y;
        o.z = acc[i][2] + bb.z; o.w = acc[i][3] + bb.w;
        if (DOELU) { o.x = elu_f(o.x); o.y = elu_f(o.y); o.z = elu_f(o.z); o.w = elu_f(o.w); }
        st4f(C + (size_t)row * 256 + gn, o);
    }
}

// edge2node aggregate, analytic edge list (bit-identical summation order).
__global__ __launch_bounds__(256)
void aggregate_kernel(const us* __restrict__ eSkip, const int* __restrict__ recv,
                      float* __restrict__ nAgg)
{
    const int t = blockIdx.x / N_;
    const int j = blockIdx.x - t * N_;
    const int c = threadIdx.x;
    const us* basep = eSkip + (size_t)t * E_ * H_ + c;
    float acc = 0.f;
    #pragma unroll
    for (int s = 0; s < N_; ++s) {
        if (s == j) continue;
        const int e = s * (N_ - 1) + (j < s ? j : j - 1);
        acc += bf2f(basep[(size_t)e * H_]);
    }
    nAgg[(size_t)blockIdx.x * H_ + c] = acc;
}

// LSTM recurrence v4: wave = r-quarter, pointwise in registers, ping-pong h
// planes, one barrier/step. Bit-identical arithmetic.
__global__ __launch_bounds__(256)
void lstm_mfma(const us* __restrict__ Gf, const us* __restrict__ Gr,
               const us* __restrict__ fWhhH, const us* __restrict__ fWhhL,
               const us* __restrict__ rWhhH, const us* __restrict__ rWhhL,
               float* __restrict__ hsF, float* __restrict__ hsR)
{
    const int NBD = (E_ + 15) / 16;
    const bool revd = (int)blockIdx.x >= NBD;
    const int blk = revd ? (int)blockIdx.x - NBD : (int)blockIdx.x;
    const int e0 = blk * 16;
    const us* G  = revd ? Gr : Gf;
    const us* WH = revd ? rWhhH : fWhhH;
    const us* WL = revd ? rWhhL : fWhhL;
    float* hs    = revd ? hsR : hsF;

    const int tid  = threadIdx.x;
    const int lane = tid & 63;
    const int w    = tid >> 6;
    const int ml   = lane & 15;
    const int q    = lane >> 4;

    __shared__ us hHi[2][16][72];
    __shared__ us hLo[2][16][72];

    short8 wfh[4][2], wfl[4][2];
    #pragma unroll
    for (int mt = 0; mt < 4; ++mt) {
        const int row = mt * 64 + w * 16 + ml;
        #pragma unroll
        for (int ks = 0; ks < 2; ++ks) {
            wfh[mt][ks] = *(const short8*)(WH + (size_t)row * 64 + ks * 32 + q * 8);
            wfl[mt][ks] = *(const short8*)(WL + (size_t)row * 64 + ks * 32 + q * 8);
        }
    }

    for (int i = tid; i < 16 * 72; i += 256) { (&hHi[0][0][0])[i] = 0; (&hLo[0][0][0])[i] = 0; }

    const int eMF = min(e0 + ml, E_ - 1);
    const bool wr = (e0 + ml) < E_;
    const int gOfs = w * 16 + q * 4;
    float4 cst = make_float4(0.f, 0.f, 0.f, 0.f);

    ushort4 gcur[4], gnxt[4];
    {
        const int tt0 = revd ? (T_ - 1) : 0;
        const us* gp = G + ((size_t)tt0 * E_ + eMF) * 256 + gOfs;
        #pragma unroll
        for (int mt = 0; mt < 4; ++mt) gcur[mt] = *(const ushort4*)(gp + mt * 64);
    }
    __syncthreads();

    for (int s = 0; s < T_; ++s) {
        const int tt = revd ? (T_ - 1 - s) : s;
        {
            const int sn = (s + 1 < T_) ? s + 1 : s;
            const int tn = revd ? (T_ - 1 - sn) : sn;
            const us* gp = G + ((size_t)tn * E_ + eMF) * 256 + gOfs;
            #pragma unroll
            for (int mt = 0; mt < 4; ++mt) gnxt[mt] = *(const ushort4*)(gp + mt * 64);
        }
        const int rb = s & 1, wb = rb ^ 1;
        short8 bh[2], bl[2];
        #pragma unroll
        for (int ks = 0; ks < 2; ++ks) {
            bh[ks] = *(const short8*)(&hHi[rb][ml][ks * 32 + q * 8]);
            bl[ks] = *(const short8*)(&hLo[rb][ml][ks * 32 + q * 8]);
        }
        f32x4 acc[4];
        #pragma unroll
        for (int mt = 0; mt < 4; ++mt) {
            acc[mt][0] = bf2f(gcur[mt].x); acc[mt][1] = bf2f(gcur[mt].y);
            acc[mt][2] = bf2f(gcur[mt].z); acc[mt][3] = bf2f(gcur[mt].w);
            #pragma unroll
            for (int ks = 0; ks < 2; ++ks) {
                acc[mt] = __builtin_amdgcn_mfma_f32_16x16x32_bf16(wfh[mt][ks], bh[ks], acc[mt], 0, 0, 0);
                acc[mt] = __builtin_amdgcn_mfma_f32_16x16x32_bf16(wfh[mt][ks], bl[ks], acc[mt], 0, 0, 0);
                acc[mt] = __builtin_amdgcn_mfma_f32_16x16x32_bf16(wfl[mt][ks], bh[ks], acc[mt], 0, 0, 0);
            }
        }
        float4 hv;
        cst.x = sig_f(acc[1][0])*cst.x + sig_f(acc[0][0])*tanh_f(acc[2][0]); hv.x = sig_f(acc[3][0])*tanh_f(cst.x);
        cst.y = sig_f(acc[1][1])*cst.y + sig_f(acc[0][1])*tanh_f(acc[2][1]); hv.y = sig_f(acc[3][1])*tanh_f(cst.y);
        cst.z = sig_f(acc[1][2])*cst.z + sig_f(acc[0][2])*tanh_f(acc[2][2]); hv.z = sig_f(acc[3][2])*tanh_f(cst.z);
        cst.w = sig_f(acc[1][3])*cst.w + sig_f(acc[0][3])*tanh_f(acc[2][3]); hv.w = sig_f(acc[3][3])*tanh_f(cst.w);
        ushort4 hh4, hl4;
        hh4.x = f2bf(hv.x); hl4.x = f2bf(hv.x - bf2f(hh4.x));
        hh4.y = f2bf(hv.y); hl4.y = f2bf(hv.y - bf2f(hh4.y));
        hh4.z = f2bf(hv.z); hl4.z = f2bf(hv.z - bf2f(hh4.z));
        hh4.w = f2bf(hv.w); hl4.w = f2bf(hv.w - bf2f(hh4.w));
        *(ushort4*)(&hHi[wb][ml][gOfs]) = hh4;
        *(ushort4*)(&hLo[wb][ml][gOfs]) = hl4;
        if (wr)
            *(float4*)(&hs[((size_t)tt * E_ + e0 + ml) * 64 + gOfs]) = hv;
        __syncthreads();
        #pragma unroll
        for (int mt = 0; mt < 4; ++mt) gcur[mt] = gnxt[mt];
    }
}

__global__ __launch_bounds__(256)
void out_kernel(const float* __restrict__ hsF, const float* __restrict__ hsR,
                const float* __restrict__ priW, const float* __restrict__ prib,
                const float* __restrict__ encW, const float* __restrict__ encb,
                float* __restrict__ out)
{
    const int idx = blockIdx.x * 256 + threadIdx.x;
    const float* f = hsF + (size_t)idx * 64;
    const float* r = hsR + (size_t)idx * 64;
    float p0 = prib[0], p1 = prib[1], q0 = encb[0], q1 = encb[1];
    #pragma unroll
    for (int k4 = 0; k4 < 16; ++k4) {
        const float4 fv = *(const float4*)(f + k4 * 4);
        const float4 rv = *(const float4*)(r + k4 * 4);
        p0 += dot4(fv, *(const float4*)(priW + k4 * 4));
        p1 += dot4(fv, *(const float4*)(priW + 64 + k4 * 4));
        q0 += dot4(fv, *(const float4*)(encW + k4 * 4))
            + dot4(rv, *(const float4*)(encW + 64 + k4 * 4));
        q1 += dot4(fv, *(const float4*)(encW + 128 + k4 * 4))
            + dot4(rv, *(const float4*)(encW + 192 + k4 * 4));
    }
    float4 o; o.x = p0; o.y = p1; o.z = q0; o.w = q1;
    *(float4*)(out + (size_t)idx * 4) = o;
}

extern "C" void kernel_launch(void* const* d_in, const int* in_sizes, int n_in,
                              void* d_out, int out_size, void* d_ws, size_t ws_size,
                              hipStream_t stream)
{
    const float* x    = (const float*)d_in[0];
    const int*   send = (const int*)d_in[2];
    const int*   recv = (const int*)d_in[3];
    const float* m1W1 = (const float*)d_in[4];  const float* m1b1 = (const float*)d_in[5];
    const float* m1W2 = (const float*)d_in[6];  const float* m1b2 = (const float*)d_in[7];
    const float* m2W1 = (const float*)d_in[8];  const float* m2b1 = (const float*)d_in[9];
    const float* m2W2 = (const float*)d_in[10]; const float* m2b2 = (const float*)d_in[11];
    const float* m3W1 = (const float*)d_in[12]; const float* m3b1 = (const float*)d_in[13];
    const float* m3W2 = (const float*)d_in[14]; const float* m3b2 = (const float*)d_in[15];
    const float* m4W1 = (const float*)d_in[16]; const float* m4b1 = (const float*)d_in[17];
    const float* m4W2 = (const float*)d_in[18]; const float* m4b2 = (const float*)d_in[19];
    const float* fWih = (const float*)d_in[20]; const float* fWhh = (const float*)d_in[21];
    const float* fbih = (const float*)d_in[22]; const float* fbhh = (const float*)d_in[23];
    const float* rWih = (const float*)d_in[24]; const float* rWhh = (const float*)d_in[25];
    const float* rbih = (const float*)d_in[26]; const float* rbhh = (const float*)d_in[27];
    const float* encW = (const float*)d_in[28]; const float* encb = (const float*)d_in[29];
    const float* priW = (const float*)d_in[30]; const float* prib = (const float*)d_in[31];

    const size_t SZN  = (size_t)TN_ * H_;
    const size_t SZE  = (size_t)TE_ * H_;
    // Ptab (TN x 512 f32) overlays n_agg+m3t exactly (both TN*2048 bytes).
    float* n_agg = (float*)d_ws;
    float* m3t   = n_agg + SZN;
    float* Ptab  = (float*)d_ws;
    us* h16      = (us*)(m3t + SZN);
    us* n3       = h16 + SZN;
    us* w2bH = n3  + SZN;          us* w2bL = w2bH + 65536;
    us* w4aH = w2bL + 65536;       us* w4aL = w4aH + 65536;
    us* w4bH = w4aL + 65536;       us* w4bL = w4bH + 65536;
    us* wfiH = w4bL + 65536;       us* wfiL = wfiH + 65536;
    us* wriH = wfiL + 65536;       us* wriL = wriH + 65536;
    us* whfH = wriL + 65536;       us* whfL = whfH + 16384;
    us* whrH = whfL + 16384;       us* whrL = whrH + 16384;
    us* bufA16 = whrL + 16384;
    us* bufB16 = bufA16 + SZE;
    us* bufC16 = bufB16 + SZE;
    float* hsF = (float*)bufC16;
    float* hsR = hsF + (size_t)TE_ * R_;
    const size_t needed = ((size_t)(bufC16 + SZE) - (size_t)d_ws);
    if (ws_size < needed) return;

    const dim3 gN(TN_ / 64, 4), gNP(TN_ / 64, 8);

    wsplit_all<<<1408, 256, 0, stream>>>(m2W2, w2bH, w2bL,
                                         m4W1, w4aH, w4aL,   // packed, strided: cols 512..767
                                         m4W2, w4bH, w4bL,
                                         fWih, wfiH, wfiL, rWih, wriH, wriL,
                                         fWhh, whfH, whfL, rWhh, whrH, whrL);

    mlp1_kernel<<<TN_ / 8, 256, 0, stream>>>(x, m1W1, m1b1, m1W2, m1b2, h16);
    // mlp2 layer 1 via node factorization
    node_proj<<<gNP, 256, 0, stream>>>(h16, m2W1, 512, Ptab);
    // mlp2 layer 2 with fused edge gather (reads Ptab directly)
    gemm_bf<<<TE_ / 64, 512, 0, stream>>>(Ptab, m2b1, send, recv, w2bH, w2bL, m2b2, bufB16);
    aggregate_kernel<<<TN_, 256, 0, stream>>>(bufB16, recv, n_agg);
    gemm_nt<true, float, float><<<gN, 256, 0, stream>>>(n_agg, m3W1, m3b1, m3t, TN_, 256);
    gemm_nt<true, float, us><<<gN, 256, 0, stream>>>(m3t, m3W2, m3b2, n3, TN_, 256);
    // mlp4 node parts
    node_proj<<<gNP, 256, 0, stream>>>(n3, m4W1, 768, Ptab);
    // fused: mlp4-L1(skip GEMM + gather) -> mlp4-L2 -> dual LSTM-input GEMM
    fused_m4<<<TE_ / 64, 512, 0, stream>>>(bufB16,
                                           w4aH, w4aL, m4b1,
                                           w4bH, w4bL, m4b2,
                                           wfiH, wfiL, fbih, fbhh,
                                           wriH, wriL, rbih, rbhh,
                                           Ptab, send, recv, bufA16, bufB16);
    lstm_mfma<<<2 * ((E_ + 15) / 16), 256, 0, stream>>>(bufA16, bufB16, whfH, whfL, whrH, whrL, hsF, hsR);
    out_kernel<<<TE_ / 256, 256, 0, stream>>>(hsF, hsR, priW, prib, encW, encb, (float*)d_out);
}